// Round 4
// baseline (195.034 us; speedup 1.0000x reference)
//
#include <hip/hip_runtime.h>
#include <hip/hip_bf16.h>
#include <stdint.h>

typedef __bf16 bf16_t;
typedef __bf16 bf16x8 __attribute__((ext_vector_type(8)));
typedef float f32x4 __attribute__((ext_vector_type(4)));
typedef float f32x16 __attribute__((ext_vector_type(16)));

#define SEQ_LEN 4096
#define D_MODEL 1024
#define N_HEAD 16

// ---------- helpers ----------

__device__ __forceinline__ void gload_lds16(const void* g, void* lds) {
  __builtin_amdgcn_global_load_lds(
      (__attribute__((address_space(1))) void*)(g),
      (__attribute__((address_space(3))) void*)(lds), 16, 0, 0);
}

__device__ __forceinline__ unsigned short f2bfu(float f) {
  __bf16 h = (__bf16)f;
  return __builtin_bit_cast(unsigned short, h);
}

__device__ __forceinline__ unsigned cvt_pk_bf16(float a, float b) {
  unsigned r;
  asm("v_cvt_pk_bf16_f32 %0, %1, %2" : "=v"(r) : "v"(a), "v"(b));
  return r;  // lo = bf16(a), hi = bf16(b)
}

// ---------- conversion kernels ----------

__global__ __launch_bounds__(256) void cvt_f32_bf16(const float* __restrict__ in,
                                                    bf16_t* __restrict__ out, int n) {
  int i = (blockIdx.x * 256 + threadIdx.x) * 4;
  if (i < n) {
    float4 v = *(const float4*)(in + i);
    unsigned int lo = (unsigned)f2bfu(v.x) | ((unsigned)f2bfu(v.y) << 16);
    unsigned int hi = (unsigned)f2bfu(v.z) | ((unsigned)f2bfu(v.w) << 16);
    uint2 pk; pk.x = lo; pk.y = hi;
    *(uint2*)(out + i) = pk;
  }
}

// W[R][C] f32 -> Wt[C][R] bf16, 64x64 tiles through LDS
__global__ __launch_bounds__(256) void transpose_cvt(const float* __restrict__ W,
                                                     bf16_t* __restrict__ Wt,
                                                     int R, int C) {
  __shared__ float tile[64][65];
  const int tc = C >> 6;
  const int bc = blockIdx.x % tc;
  const int br = blockIdx.x / tc;
  #pragma unroll
  for (int p = 0; p < 16; ++p) {
    int idx = p * 256 + threadIdx.x;
    int i = idx >> 6, j = idx & 63;
    tile[i][j] = W[(size_t)(br * 64 + i) * C + bc * 64 + j];
  }
  __syncthreads();
  #pragma unroll
  for (int p = 0; p < 16; ++p) {
    int idx = p * 256 + threadIdx.x;
    int jj = idx >> 6, ii = idx & 63;
    Wt[(size_t)(bc * 64 + jj) * R + br * 64 + ii] = (bf16_t)tile[ii][jj];
  }
}

// ---------- GEMM: C[M][N] = A[M][K] * Bt[N][K]^T + bias ----------
// VSPLIT: columns >= 2048 (the V third of QKV) are written TRANSPOSED to
// vtout[col-2048][row] instead of row-major Cout.

template <bool OUT_BF16, bool VSPLIT>
__global__ __launch_bounds__(256) void gemm_bt(const bf16_t* __restrict__ A,
                                               const bf16_t* __restrict__ Bt,
                                               const float* __restrict__ bias,
                                               void* __restrict__ Cout,
                                               bf16_t* __restrict__ vtout,
                                               int M, int N, int K) {
  __shared__ bf16_t As[128 * 32];
  __shared__ bf16_t Bs[128 * 32];
  const int tid = threadIdx.x;
  const int lane = tid & 63;
  const int w = tid >> 6;
  const int wr = (w >> 1) * 64;
  const int wc = (w & 1) * 64;
  const int i16 = lane & 15;
  const int g = lane >> 4;
  const int ntn = N >> 7;
  const int bm = blockIdx.x / ntn;
  const int bn = blockIdx.x % ntn;
  const bf16_t* Abase = A + (size_t)(bm * 128) * K;
  const bf16_t* Bbase = Bt + (size_t)(bn * 128) * K;

  f32x4 acc[4][4];
  #pragma unroll
  for (int m = 0; m < 4; ++m)
    #pragma unroll
    for (int n = 0; n < 4; ++n)
      acc[m][n] = (f32x4){0.f, 0.f, 0.f, 0.f};

  for (int kt = 0; kt < K; kt += 32) {
    __syncthreads();
    #pragma unroll
    for (int p = 0; p < 2; ++p) {
      int idx = p * 256 + tid;
      int row = idx >> 2, ch = idx & 3;
      gload_lds16(Abase + (size_t)row * K + kt + ch * 8, (char*)As + idx * 16);
      gload_lds16(Bbase + (size_t)row * K + kt + ch * 8, (char*)Bs + idx * 16);
    }
    __syncthreads();
    bf16x8 af[4], bq[4];
    #pragma unroll
    for (int m = 0; m < 4; ++m)
      af[m] = *(const bf16x8*)(As + (wr + m * 16 + i16) * 32 + g * 8);
    #pragma unroll
    for (int n = 0; n < 4; ++n)
      bq[n] = *(const bf16x8*)(Bs + (wc + n * 16 + i16) * 32 + g * 8);
    #pragma unroll
    for (int m = 0; m < 4; ++m)
      #pragma unroll
      for (int n = 0; n < 4; ++n)
        acc[m][n] = __builtin_amdgcn_mfma_f32_16x16x32_bf16(af[m], bq[n], acc[m][n], 0, 0, 0);
  }

  #pragma unroll
  for (int m = 0; m < 4; ++m) {
    #pragma unroll
    for (int n = 0; n < 4; ++n) {
      int col = bn * 128 + wc + n * 16 + i16;
      float bv = bias ? bias[col] : 0.f;
      int row0 = bm * 128 + wr + m * 16 + g * 4;
      if (VSPLIT && col >= 2048) {
        uint2 pk;
        pk.x = cvt_pk_bf16(acc[m][n][0] + bv, acc[m][n][1] + bv);
        pk.y = cvt_pk_bf16(acc[m][n][2] + bv, acc[m][n][3] + bv);
        *(uint2*)(vtout + (size_t)(col - 2048) * 4096 + row0) = pk;
      } else {
        #pragma unroll
        for (int r = 0; r < 4; ++r) {
          float v = acc[m][n][r] + bv;
          if (OUT_BF16)
            ((bf16_t*)Cout)[(size_t)(row0 + r) * N + col] = (bf16_t)v;
          else
            ((float*)Cout)[(size_t)(row0 + r) * N + col] = v;
        }
      }
    }
  }
}

// ---------- causal flash attention: independent single-wave blocks ----------
// Block = 1 wave (64 threads) owning 32 q-rows of one head. KV tile = 32.
// Own double-buffered K/V^T LDS; staging via global_load_lds; NO barriers —
// per-wave counted s_waitcnt vmcnt(8) keeps next tile's loads in flight
// across the current tile's compute.
// S^T = mfma_32x32(K, Q): lane q = lane&31, keys (r&3)+8*(r>>2)+4*(lane>>5).
// O^T = mfma_32x32(V^T, P^T).

__device__ __forceinline__ void stage_kv(const bf16_t* __restrict__ qkv,
                                         const bf16_t* __restrict__ vt,
                                         char* KsB, char* VsB,
                                         int kv, int h, int tid) {
  const int krow = tid >> 3;                       // 0..7
  const int ksch = (tid & 7) ^ krow;               // K pre-swizzled 8-elem chunk
  const int vrow = tid >> 2;                       // 0..15
  const int vsch = (tid & 3) ^ ((tid >> 3) & 3);   // V pre-swizzled 8-elem chunk
  #pragma unroll
  for (int i = 0; i < 4; ++i) {
    gload_lds16(qkv + (size_t)(kv + i * 8 + krow) * 3072 + 1024 + h * 64 + ksch * 8,
                KsB + i * 1024 + tid * 16);
    gload_lds16(vt + (size_t)(h * 64 + i * 16 + vrow) * 4096 + kv + vsch * 8,
                VsB + i * 1024 + tid * 16);
  }
}

__global__ __launch_bounds__(64) void attn_fwd(const bf16_t* __restrict__ qkv,
                                               const bf16_t* __restrict__ vt,
                                               bf16_t* __restrict__ aout) {
  __shared__ __align__(16) bf16_t Ks[2][32 * 64];   // [keys][dh], 128B rows, XOR-swz
  __shared__ __align__(16) bf16_t Vs[2][64 * 32];   // [dh][keys], 64B rows, chunk-swz
  const int tid = threadIdx.x;
  const int l31 = tid & 31;
  const int hi = tid >> 5;
  const int h = blockIdx.x & 15;
  const int j = 127 - (blockIdx.x >> 4);   // q-tile index, heavy first
  const int q = j * 32 + l31;
  const float sc = 0.18033688011112042f;   // log2(e)/sqrt(64)

  // Q B-frags: qf[ks][e] = Q[q][ks*16 + hi*8 + e]
  bf16x8 qf[4];
  #pragma unroll
  for (int ks = 0; ks < 4; ++ks)
    qf[ks] = *(const bf16x8*)(qkv + (size_t)q * 3072 + h * 64 + ks * 16 + hi * 8);

  f32x16 ot0, ot1;
  #pragma unroll
  for (int r = 0; r < 16; ++r) { ot0[r] = 0.f; ot1[r] = 0.f; }
  float m_run = -1e30f, l_run = 0.f;

  const int nt = j + 1;
  stage_kv(qkv, vt, (char*)Ks[0], (char*)Vs[0], 0, h, tid);
  int cur = 0;
  const int ksw = (l31 & 7) << 4;          // K read swizzle
  const int vq = (l31 >> 1) & 3;           // V read chunk swizzle

  for (int t = 0; t < nt; ++t) {
    if (t + 1 < nt) {
      stage_kv(qkv, vt, (char*)Ks[cur ^ 1], (char*)Vs[cur ^ 1], (t + 1) * 32, h, tid);
      asm volatile("s_waitcnt vmcnt(8)" ::: "memory");
    } else {
      asm volatile("s_waitcnt vmcnt(0)" ::: "memory");
    }
    const char* Kc = (const char*)Ks[cur];
    const char* Vc = (const char*)Vs[cur];

    // S^T = K . Q^T over d=64
    f32x16 s;
    #pragma unroll
    for (int r = 0; r < 16; ++r) s[r] = 0.f;
    #pragma unroll
    for (int ks = 0; ks < 4; ++ks) {
      bf16x8 kf = *(const bf16x8*)(Kc + ((l31 * 128 + ks * 32 + hi * 16) ^ ksw));
      s = __builtin_amdgcn_mfma_f32_32x32x16_bf16(kf, qf[ks], s, 0, 0, 0);
    }

    // causal mask: only the diagonal tile (t == j)
    if (t == nt - 1) {
      #pragma unroll
      for (int r = 0; r < 16; ++r) {
        int c = (r & 3) + 8 * (r >> 2) + 4 * hi;
        if (c > l31) s[r] = -1e30f;
      }
    }

    // row max: in-reg tree + one cross-half exchange
    float mm[8];
    #pragma unroll
    for (int r = 0; r < 8; ++r) mm[r] = fmaxf(s[r], s[r + 8]);
    #pragma unroll
    for (int r = 0; r < 4; ++r) mm[r] = fmaxf(mm[r], mm[r + 4]);
    float tmax = fmaxf(fmaxf(mm[0], mm[1]), fmaxf(mm[2], mm[3]));
    tmax = fmaxf(tmax, __shfl_xor(tmax, 32));

    // T13 defer-max
    if (!__all(sc * (tmax - m_run) <= 8.0f)) {
      float mnew = fmaxf(m_run, tmax);
      float alpha = __builtin_amdgcn_exp2f(sc * (m_run - mnew));
      l_run *= alpha;
      #pragma unroll
      for (int r = 0; r < 16; ++r) { ot0[r] *= alpha; ot1[r] *= alpha; }
      m_run = mnew;
    }

    // P = exp2(sc*s - sc*m)
    float nscm = -sc * m_run;
    #pragma unroll
    for (int r = 0; r < 16; ++r)
      s[r] = __builtin_amdgcn_exp2f(fmaf(s[r], sc, nscm));

    // row sum
    float sm[8];
    #pragma unroll
    for (int r = 0; r < 8; ++r) sm[r] = s[r] + s[r + 8];
    #pragma unroll
    for (int r = 0; r < 4; ++r) sm[r] = sm[r] + sm[r + 4];
    float rs = (sm[0] + sm[1]) + (sm[2] + sm[3]);
    rs += __shfl_xor(rs, 32);
    l_run += rs;

    // T12: pack P to bf16 + one half-swap -> PV B-frags (keys g2*16+hi*8+e)
    bf16x8 pb[2];
    #pragma unroll
    for (int g2 = 0; g2 < 2; ++g2) {
      const int r0 = g2 * 8;
      unsigned a0 = cvt_pk_bf16(s[r0 + 0], s[r0 + 1]);
      unsigned a1 = cvt_pk_bf16(s[r0 + 2], s[r0 + 3]);
      unsigned b0 = cvt_pk_bf16(s[r0 + 4], s[r0 + 5]);
      unsigned b1 = cvt_pk_bf16(s[r0 + 6], s[r0 + 7]);
      unsigned X0 = hi ? a0 : b0;
      unsigned X1 = hi ? a1 : b1;
      unsigned Y0 = __shfl_xor(X0, 32);
      unsigned Y1 = __shfl_xor(X1, 32);
      uint4 f;
      f.x = hi ? Y0 : a0;
      f.y = hi ? Y1 : a1;
      f.z = hi ? b0 : Y0;
      f.w = hi ? b1 : Y1;
      pb[g2] = __builtin_bit_cast(bf16x8, f);
    }

    // O^T += V^T . P^T   (dh = dt*32 + l31)
    #pragma unroll
    for (int g2 = 0; g2 < 2; ++g2) {
      bf16x8 v0 = *(const bf16x8*)(Vc + (l31 * 64 + (((g2 * 2 + hi) ^ vq) << 4)));
      ot0 = __builtin_amdgcn_mfma_f32_32x32x16_bf16(v0, pb[g2], ot0, 0, 0, 0);
      bf16x8 v1 = *(const bf16x8*)(Vc + ((32 + l31) * 64 + (((g2 * 2 + hi) ^ vq) << 4)));
      ot1 = __builtin_amdgcn_mfma_f32_32x32x16_bf16(v1, pb[g2], ot1, 0, 0, 0);
    }

    cur ^= 1;
  }

  // epilogue: lane q, dh = dt*32 + 8*rq + 4*hi + {0..3}
  float inv = 1.0f / l_run;
  #pragma unroll
  for (int dt = 0; dt < 2; ++dt) {
    const f32x16& o = dt ? ot1 : ot0;
    #pragma unroll
    for (int rq = 0; rq < 4; ++rq) {
      unsigned lo = cvt_pk_bf16(o[4 * rq + 0] * inv, o[4 * rq + 1] * inv);
      unsigned hi2 = cvt_pk_bf16(o[4 * rq + 2] * inv, o[4 * rq + 3] * inv);
      uint2 pk2; pk2.x = lo; pk2.y = hi2;
      *(uint2*)(aout + (size_t)q * 1024 + h * 64 + dt * 32 + 8 * rq + 4 * hi) = pk2;
    }
  }
}

// ---------- launch ----------

extern "C" void kernel_launch(void* const* d_in, const int* in_sizes, int n_in,
                              void* d_out, int out_size, void* d_ws, size_t ws_size,
                              hipStream_t stream) {
  const float* x     = (const float*)d_in[0];
  const float* w_qkv = (const float*)d_in[1];
  const float* b_qkv = (const float*)d_in[2];
  const float* w_o   = (const float*)d_in[3];
  const float* b_o   = (const float*)d_in[4];

  char* ws = (char*)d_ws;
  bf16_t* xh    = (bf16_t*)(ws);                          //  8 MiB
  bf16_t* wqkvT = (bf16_t*)(ws + 8388608);                //  6 MiB
  bf16_t* woT   = (bf16_t*)(ws + 14680064);               //  2 MiB
  bf16_t* qkv   = (bf16_t*)(ws + 16777216);               // 24 MiB (Q,K thirds used)
  bf16_t* aout  = (bf16_t*)(ws + 41943040);               //  8 MiB
  bf16_t* vtg   = (bf16_t*)(ws + 50331648);               //  8 MiB  V^T [1024][4096]

  cvt_f32_bf16<<<(SEQ_LEN * D_MODEL) / 1024, 256, 0, stream>>>(x, xh, SEQ_LEN * D_MODEL);
  transpose_cvt<<<(1024 / 64) * (3072 / 64), 256, 0, stream>>>(w_qkv, wqkvT, 1024, 3072);
  transpose_cvt<<<(1024 / 64) * (1024 / 64), 256, 0, stream>>>(w_o, woT, 1024, 1024);

  gemm_bt<true, true><<<(4096 / 128) * (3072 / 128), 256, 0, stream>>>(
      xh, wqkvT, b_qkv, (void*)qkv, vtg, 4096, 3072, 1024);

  attn_fwd<<<N_HEAD * (SEQ_LEN / 32), 64, 0, stream>>>(qkv, vtg, aout);

  gemm_bt<false, false><<<(4096 / 128) * (1024 / 128), 256, 0, stream>>>(
      aout, woT, b_o, d_out, nullptr, 4096, 1024, 1024);
}